// Round 13
// baseline (455.097 us; speedup 1.0000x reference)
//
#include <hip/hip_runtime.h>

#define B_ 256
#define T_ 500
#define N_ 256
#define BN_ 65536            // B_*N_
#define STP_ 196608          // 3*B_*N_ (states per-t stride)
#define TW 64                // t-window per chunk
#define NCHUNK 8             // ceil(500/64)

// ---------------------------------------------------------------------------
// Fused GEMM + Izhikevich scan. One block per batch b (256 blocks x 256 thr).
// R12 kernel + explicitly software-pipelined phase-G kk-loop: fragments for
// kk+1 are loaded into registers BEFORE the kk FMA block (load->FMA->rotate),
// hiding the ~120-cy ds_read_b128 latency under the 128-cy FMA block --
// at 1 wave/SIMD the compiler was leaving that latency exposed per-kk.
// Same fmaf chain per output (k-ascending) -> bit-identical I.
// Phases A (async), W-stage, S (scan), dotw, li: byte-identical to R12.
// ---------------------------------------------------------------------------
__global__ __launch_bounds__(256)
void fused_snn_kernel(const float* __restrict__ X, const float* __restrict__ W1,
                      float* __restrict__ out_s, float* __restrict__ states,
                      float* __restrict__ out_dec,
                      const float* __restrict__ st_snn, const float* __restrict__ st_li,
                      const float* __restrict__ W2,
                      const float* __restrict__ pa, const float* __restrict__ pb,
                      const float* __restrict__ pc, const float* __restrict__ pd,
                      const float* __restrict__ pv0, const float* __restrict__ pv1,
                      const float* __restrict__ pv2, const float* __restrict__ ptau,
                      const float* __restrict__ pth, const float* __restrict__ pleak) {
    __shared__ float Al[TW * 256];       // 64 KB: X (k-major) then I[t][n]
    __shared__ float Ws[2][16 * 256];    // 32 KB: W1t slice double buffer
    __shared__ float dotw[T_][4];        //  8 KB: per-wave dot partials

    const int bb   = blockIdx.x;
    const int tid  = threadIdx.x;
    const int w    = tid >> 6;
    const int lane = tid & 63;
    const int boff = bb * 256 + tid;

    // scan per-thread state & params
    float v = st_snn[boff];
    float u = st_snn[BN_ + boff];
    const float a_   = pa[tid];
    const float b_   = pb[tid];
    const float c_   = pc[tid];
    const float d_   = pd[tid];
    const float v0_  = pv0[tid];
    const float v1_  = pv1[tid];
    const float v2_  = pv2[tid];
    const float coef = (1.0f / ptau[tid]) * a_;  // (DT/tau_u)*a, DT=1
    const float th_  = pth[tid];
    const float w2_  = W2[tid];

    // GEMM microtile: 8 t-groups x 32 n-groups, 8x8 per thread
    const int g   = tid >> 5;            // t rows 8g..8g+7
    const int tg  = g << 3;
    const int h4  = (tid & 31) << 2;     // n cols h4..h4+3 and h4+128..h4+131

    const float* Xb = X + (size_t)bb * (T_ * 256);
    const int tl = tid & 63;             // A-stage t_loc
    const int wq = (tid >> 6) << 2;      // A-stage k sub-quad

    // W ks=0 slice held permanently in regs (chunk-invariant)
    const float* Wr0 = W1 + (size_t)tid * 256;
    const float4 z0 = *(const float4*)(Wr0 + 0);
    const float4 z1 = *(const float4*)(Wr0 + 4);
    const float4 z2 = *(const float4*)(Wr0 + 8);
    const float4 z3 = *(const float4*)(Wr0 + 12);

    // async A-stage: prologue issue for chunk 0
    float4 ra[16];
    {
        const int tsrc = ((tl < TW) ? tl : (TW - 1));   // valid=64 for chunk 0
        const float* Xrow = Xb + (size_t)tsrc * 256;
#pragma unroll
        for (int r = 0; r < 16; ++r)
            ra[r] = *(const float4*)(Xrow + r * 16 + wq);
    }

    for (int cc = 0; cc < NCHUNK; ++cc) {
        const int t0    = cc * TW;
        const int valid = (T_ - t0 < TW) ? (T_ - t0) : TW;

        // ---------------- phase A: regs -> Al[k][t] (write-late) ------------
#pragma unroll
        for (int r = 0; r < 16; ++r) {
            const int k = r * 16 + wq;
            Al[(k + 0) * 64 + tl] = ra[r].x;
            Al[(k + 1) * 64 + tl] = ra[r].y;
            Al[(k + 2) * 64 + tl] = ra[r].z;
            Al[(k + 3) * 64 + tl] = ra[r].w;
        }
        // stage W slice ks=0 into Ws[0] from held regs (Ws[kk][n]=W1[n][kk])
        {
            float* Wd = &Ws[0][0];
            Wd[ 0*256+tid]=z0.x; Wd[ 1*256+tid]=z0.y; Wd[ 2*256+tid]=z0.z; Wd[ 3*256+tid]=z0.w;
            Wd[ 4*256+tid]=z1.x; Wd[ 5*256+tid]=z1.y; Wd[ 6*256+tid]=z1.z; Wd[ 7*256+tid]=z1.w;
            Wd[ 8*256+tid]=z2.x; Wd[ 9*256+tid]=z2.y; Wd[10*256+tid]=z2.z; Wd[11*256+tid]=z2.w;
            Wd[12*256+tid]=z3.x; Wd[13*256+tid]=z3.y; Wd[14*256+tid]=z3.z; Wd[15*256+tid]=z3.w;
        }
        __syncthreads();

        // ---------------- phase G: block GEMM, 8x8 acc, kk-pipelined --------
        float acc[8][8];
#pragma unroll
        for (int i = 0; i < 8; ++i)
#pragma unroll
            for (int j = 0; j < 8; ++j) acc[i][j] = 0.f;

        for (int ks = 0; ks < 16; ++ks) {
            float4 w0, w1, w2v, w3;
            if (ks < 15) {               // next-slice W loads (R4 verbatim)
                const float* Wr = W1 + (size_t)tid * 256 + (ks + 1) * 16;
                w0 = *(const float4*)(Wr + 0);
                w1 = *(const float4*)(Wr + 4);
                w2v = *(const float4*)(Wr + 8);
                w3 = *(const float4*)(Wr + 12);
            }
            const float* Wc = &Ws[ks & 1][0];
            const int kbase = ks << 4;

            // prologue: kk=0 fragments
            float4 a0 = *(const float4*)&Al[kbase * 64 + tg];
            float4 a1 = *(const float4*)&Al[kbase * 64 + tg + 4];
            float4 b0 = *(const float4*)&Wc[h4];
            float4 b1 = *(const float4*)&Wc[h4 + 128];

#pragma unroll
            for (int kk = 0; kk < 15; ++kk) {
                // issue kk+1 loads BEFORE the kk FMA block (latency hidden)
                const float4 na0 = *(const float4*)&Al[(kbase + kk + 1) * 64 + tg];
                const float4 na1 = *(const float4*)&Al[(kbase + kk + 1) * 64 + tg + 4];
                const float4 nb0 = *(const float4*)&Wc[(kk + 1) * 256 + h4];
                const float4 nb1 = *(const float4*)&Wc[(kk + 1) * 256 + h4 + 128];
                const float avr[8] = {a0.x, a0.y, a0.z, a0.w, a1.x, a1.y, a1.z, a1.w};
                const float bvr[8] = {b0.x, b0.y, b0.z, b0.w, b1.x, b1.y, b1.z, b1.w};
#pragma unroll
                for (int i = 0; i < 8; ++i)
#pragma unroll
                    for (int j = 0; j < 8; ++j)
                        acc[i][j] += avr[i] * bvr[j];
                a0 = na0; a1 = na1; b0 = nb0; b1 = nb1;
            }
            {   // epilogue: kk=15 FMA block
                const float avr[8] = {a0.x, a0.y, a0.z, a0.w, a1.x, a1.y, a1.z, a1.w};
                const float bvr[8] = {b0.x, b0.y, b0.z, b0.w, b1.x, b1.y, b1.z, b1.w};
#pragma unroll
                for (int i = 0; i < 8; ++i)
#pragma unroll
                    for (int j = 0; j < 8; ++j)
                        acc[i][j] += avr[i] * bvr[j];
            }

            if (ks < 15) {               // LDS writes after FMAs (R4 verbatim)
                float* Wd = &Ws[(ks + 1) & 1][0];
                Wd[ 0*256+tid]=w0.x; Wd[ 1*256+tid]=w0.y; Wd[ 2*256+tid]=w0.z; Wd[ 3*256+tid]=w0.w;
                Wd[ 4*256+tid]=w1.x; Wd[ 5*256+tid]=w1.y; Wd[ 6*256+tid]=w1.z; Wd[ 7*256+tid]=w1.w;
                Wd[ 8*256+tid]=w2v.x; Wd[ 9*256+tid]=w2v.y; Wd[10*256+tid]=w2v.z; Wd[11*256+tid]=w2v.w;
                Wd[12*256+tid]=w3.x; Wd[13*256+tid]=w3.y; Wd[14*256+tid]=w3.z; Wd[15*256+tid]=w3.w;
            }
            __syncthreads();             // also separates ks=15 Al reads from I-write
        }

        // ---------------- phase I: acc -> Al as I[t][n] ----------------
#pragma unroll
        for (int i = 0; i < 8; ++i) {
            const int t = tg + i;
            *(float4*)&Al[t * 256 + h4] =
                make_float4(acc[i][0], acc[i][1], acc[i][2], acc[i][3]);
            *(float4*)&Al[t * 256 + h4 + 128] =
                make_float4(acc[i][4], acc[i][5], acc[i][6], acc[i][7]);
        }
        __syncthreads();

        // ---------------- async A: issue next chunk's X loads (early) -------
        if (cc + 1 < NCHUNK) {
            const int t0n    = (cc + 1) * TW;
            const int validn = (T_ - t0n < TW) ? (T_ - t0n) : TW;
            const int tsrc   = t0n + ((tl < validn) ? tl : (validn - 1));
            const float* Xrow = Xb + (size_t)tsrc * 256;
#pragma unroll
            for (int r = 0; r < 16; ++r)
                ra[r] = *(const float4*)(Xrow + r * 16 + wq);
        }

        // ---------------- phase S: scan (R4 verbatim) ----------------
        {
            float Inx = Al[tid];         // q=0 prefetch
            for (int q = 0; q < valid; ++q) {
                const float Icur = Inx;
                if (q + 1 < valid) Inx = Al[(q + 1) * 256 + tid];
                const int t = t0 + q;
                const size_t pbase = (size_t)t * STP_ + boff;

                const float vm = v + (((v2_ * v * v + v1_ * v) + v0_ - u) + Icur);
                const float um = u + coef * (b_ * v - u);
                const bool  sp = (vm - th_) > 0.f;
                const float s  = sp ? 1.f : 0.f;
                v = sp ? c_ : vm;        // == vm*(1-s)+s*c exactly, s in {0,1}
                u = sp ? (um + d_) : um; // == um + s*d

                states[pbase]           = v;
                states[pbase + BN_]     = u;
                states[pbase + 2 * BN_] = s;
                out_s[(size_t)t * BN_ + boff] = s;

                float ds = s * w2_;
                ds += __shfl_xor(ds, 1);  ds += __shfl_xor(ds, 2);
                ds += __shfl_xor(ds, 4);  ds += __shfl_xor(ds, 8);
                ds += __shfl_xor(ds, 16); ds += __shfl_xor(ds, 32);
                if (lane == 0) dotw[t][w] = ds;
            }
        }
        __syncthreads();                 // Al reads done before next A-stage
    }

    // ---------------- li recurrence (thread 0, R4 verbatim) ----------------
    if (tid == 0) {
        const float lk_  = pleak[0];
        const float olk_ = 1.0f - lk_;
        float li = st_li[bb];
        for (int t = 0; t < T_; ++t) {
            const float dot = (dotw[t][0] + dotw[t][1]) + (dotw[t][2] + dotw[t][3]);
            li = lk_ * li + olk_ * dot;
            out_dec[(size_t)t * 256 + bb] = li;
        }
    }
}

// ---------------------------------------------------------------------------
extern "C" void kernel_launch(void* const* d_in, const int* in_sizes, int n_in,
                              void* d_out, int out_size, void* d_ws, size_t ws_size,
                              hipStream_t stream) {
    const float* input  = (const float*)d_in[0];   // [B,T,N]
    const float* st_snn = (const float*)d_in[1];   // [3,B,N]
    const float* st_li  = (const float*)d_in[2];   // [B,1]
    const float* W1     = (const float*)d_in[3];   // [N,N]
    const float* W2     = (const float*)d_in[4];   // [1,N]
    const float* pa     = (const float*)d_in[5];
    const float* pb     = (const float*)d_in[6];
    const float* pc     = (const float*)d_in[7];
    const float* pd     = (const float*)d_in[8];
    const float* pv0    = (const float*)d_in[9];
    const float* pv1    = (const float*)d_in[10];
    const float* pv2    = (const float*)d_in[11];
    const float* ptau   = (const float*)d_in[12];
    const float* pth    = (const float*)d_in[13];
    const float* pleak  = (const float*)d_in[14];

    float* out        = (float*)d_out;
    float* out_s      = out;                                        // [500,256,256]
    float* out_states = out + (size_t)T_ * BN_;                     // [500,3,256,256]
    float* out_dec    = out + (size_t)T_ * BN_ + (size_t)T_ * STP_; // [500,256]

    fused_snn_kernel<<<dim3(B_), dim3(256), 0, stream>>>(
        input, W1, out_s, out_states, out_dec, st_snn, st_li, W2,
        pa, pb, pc, pd, pv0, pv1, pv2, ptau, pth, pleak);
}

// Round 14
// 383.176 us; speedup vs baseline: 1.1877x; 1.1877x over previous
//
#include <hip/hip_runtime.h>

#define B_ 256
#define T_ 500
#define N_ 256
#define BN_ 65536            // B_*N_
#define STP_ 196608          // 3*B_*N_ (states per-t stride)
#define TW 64                // t-window per chunk
#define NCHUNK 8             // ceil(500/64)

// ---------------------------------------------------------------------------
// Fused GEMM + Izhikevich scan. One block per batch b (256 blocks x 256 thr).
// R12 base (448 us) + two changes:
//  1. vm/um CANONICALIZED with explicit __builtin_fmaf replicating LLVM's
//     LHS-first contraction (the R4-lineage codegen). This pins the spike
//     numerics against context-dependent re-contraction -- the mechanism
//     behind R5/R8's identical single-site flips (absmax 103.25 both).
//  2. With s pinned, the 6-dependent-ds_bpermute reduction per step is
//     replaced by one __ballot -> dotm[t][w]; masks are converted to dots
//     in a parallel end-pass (li has no feedback; reorder error ~1e-6).
// GEMM/staging identical to R12 -> bit-identical I.
// ---------------------------------------------------------------------------
__global__ __launch_bounds__(256)
void fused_snn_kernel(const float* __restrict__ X, const float* __restrict__ W1,
                      float* __restrict__ out_s, float* __restrict__ states,
                      float* __restrict__ out_dec,
                      const float* __restrict__ st_snn, const float* __restrict__ st_li,
                      const float* __restrict__ W2,
                      const float* __restrict__ pa, const float* __restrict__ pb,
                      const float* __restrict__ pc, const float* __restrict__ pd,
                      const float* __restrict__ pv0, const float* __restrict__ pv1,
                      const float* __restrict__ pv2, const float* __restrict__ ptau,
                      const float* __restrict__ pth, const float* __restrict__ pleak) {
    __shared__ float Al[TW * 256];              // 64 KB: X (k-major) then I[t][n]
    __shared__ float Ws[2][16 * 256];           // 32 KB: W1t slice double buffer
    __shared__ unsigned long long dotm[T_][4];  // ~16 KB: per-wave spike masks
    __shared__ float dotf[T_][4];               //  8 KB: per-wave dot partials
    __shared__ float w2l[256];                  //  1 KB

    const int bb   = blockIdx.x;
    const int tid  = threadIdx.x;
    const int w    = tid >> 6;
    const int lane = tid & 63;
    const int boff = bb * 256 + tid;

    // scan per-thread state & params
    float v = st_snn[boff];
    float u = st_snn[BN_ + boff];
    const float a_   = pa[tid];
    const float b_   = pb[tid];
    const float c_   = pc[tid];
    const float d_   = pd[tid];
    const float v0_  = pv0[tid];
    const float v1_  = pv1[tid];
    const float v2_  = pv2[tid];
    const float coef = (1.0f / ptau[tid]) * a_;  // (DT/tau_u)*a, DT=1
    const float th_  = pth[tid];
    w2l[tid] = W2[tid];

    // GEMM microtile: 8 t-groups x 32 n-groups, 8x8 per thread
    const int g   = tid >> 5;            // t rows 8g..8g+7
    const int tg  = g << 3;
    const int h4  = (tid & 31) << 2;     // n cols h4..h4+3 and h4+128..h4+131

    const float* Xb = X + (size_t)bb * (T_ * 256);
    const int tl = tid & 63;             // A-stage t_loc
    const int wq = (tid >> 6) << 2;      // A-stage k sub-quad

    // W ks=0 slice held permanently in regs (chunk-invariant)
    const float* Wr0 = W1 + (size_t)tid * 256;
    const float4 z0 = *(const float4*)(Wr0 + 0);
    const float4 z1 = *(const float4*)(Wr0 + 4);
    const float4 z2 = *(const float4*)(Wr0 + 8);
    const float4 z3 = *(const float4*)(Wr0 + 12);

    // async A-stage: prologue issue for chunk 0
    float4 ra[16];
    {
        const int tsrc = ((tl < TW) ? tl : (TW - 1));   // valid=64 for chunk 0
        const float* Xrow = Xb + (size_t)tsrc * 256;
#pragma unroll
        for (int r = 0; r < 16; ++r)
            ra[r] = *(const float4*)(Xrow + r * 16 + wq);
    }

    for (int cc = 0; cc < NCHUNK; ++cc) {
        const int t0    = cc * TW;
        const int valid = (T_ - t0 < TW) ? (T_ - t0) : TW;

        // ---------------- phase A: regs -> Al[k][t] (write-late) ------------
#pragma unroll
        for (int r = 0; r < 16; ++r) {
            const int k = r * 16 + wq;
            Al[(k + 0) * 64 + tl] = ra[r].x;
            Al[(k + 1) * 64 + tl] = ra[r].y;
            Al[(k + 2) * 64 + tl] = ra[r].z;
            Al[(k + 3) * 64 + tl] = ra[r].w;
        }
        // stage W slice ks=0 into Ws[0] from held regs (Ws[kk][n]=W1[n][kk])
        {
            float* Wd = &Ws[0][0];
            Wd[ 0*256+tid]=z0.x; Wd[ 1*256+tid]=z0.y; Wd[ 2*256+tid]=z0.z; Wd[ 3*256+tid]=z0.w;
            Wd[ 4*256+tid]=z1.x; Wd[ 5*256+tid]=z1.y; Wd[ 6*256+tid]=z1.z; Wd[ 7*256+tid]=z1.w;
            Wd[ 8*256+tid]=z2.x; Wd[ 9*256+tid]=z2.y; Wd[10*256+tid]=z2.z; Wd[11*256+tid]=z2.w;
            Wd[12*256+tid]=z3.x; Wd[13*256+tid]=z3.y; Wd[14*256+tid]=z3.z; Wd[15*256+tid]=z3.w;
        }
        __syncthreads();

        // ---------------- phase G: block GEMM, 8x8 acc in regs --------------
        float acc[8][8];
#pragma unroll
        for (int i = 0; i < 8; ++i)
#pragma unroll
            for (int j = 0; j < 8; ++j) acc[i][j] = 0.f;

        for (int ks = 0; ks < 16; ++ks) {
            float4 w0, w1, w2v, w3;
            if (ks < 15) {               // next-slice W loads (R4 verbatim)
                const float* Wr = W1 + (size_t)tid * 256 + (ks + 1) * 16;
                w0 = *(const float4*)(Wr + 0);
                w1 = *(const float4*)(Wr + 4);
                w2v = *(const float4*)(Wr + 8);
                w3 = *(const float4*)(Wr + 12);
            }
            const float* Wc = &Ws[ks & 1][0];
            const int kbase = ks << 4;
#pragma unroll
            for (int kk = 0; kk < 16; ++kk) {
                const float4 a0 = *(const float4*)&Al[(kbase + kk) * 64 + tg];
                const float4 a1 = *(const float4*)&Al[(kbase + kk) * 64 + tg + 4];
                const float4 b0 = *(const float4*)&Wc[kk * 256 + h4];
                const float4 b1 = *(const float4*)&Wc[kk * 256 + h4 + 128];
                const float avr[8] = {a0.x, a0.y, a0.z, a0.w, a1.x, a1.y, a1.z, a1.w};
                const float bvr[8] = {b0.x, b0.y, b0.z, b0.w, b1.x, b1.y, b1.z, b1.w};
#pragma unroll
                for (int i = 0; i < 8; ++i)
#pragma unroll
                    for (int j = 0; j < 8; ++j)
                        acc[i][j] += avr[i] * bvr[j];
            }
            if (ks < 15) {               // LDS writes after FMAs (R4 verbatim)
                float* Wd = &Ws[(ks + 1) & 1][0];
                Wd[ 0*256+tid]=w0.x; Wd[ 1*256+tid]=w0.y; Wd[ 2*256+tid]=w0.z; Wd[ 3*256+tid]=w0.w;
                Wd[ 4*256+tid]=w1.x; Wd[ 5*256+tid]=w1.y; Wd[ 6*256+tid]=w1.z; Wd[ 7*256+tid]=w1.w;
                Wd[ 8*256+tid]=w2v.x; Wd[ 9*256+tid]=w2v.y; Wd[10*256+tid]=w2v.z; Wd[11*256+tid]=w2v.w;
                Wd[12*256+tid]=w3.x; Wd[13*256+tid]=w3.y; Wd[14*256+tid]=w3.z; Wd[15*256+tid]=w3.w;
            }
            __syncthreads();             // also separates ks=15 Al reads from I-write
        }

        // ---------------- phase I: acc -> Al as I[t][n] ----------------
#pragma unroll
        for (int i = 0; i < 8; ++i) {
            const int t = tg + i;
            *(float4*)&Al[t * 256 + h4] =
                make_float4(acc[i][0], acc[i][1], acc[i][2], acc[i][3]);
            *(float4*)&Al[t * 256 + h4 + 128] =
                make_float4(acc[i][4], acc[i][5], acc[i][6], acc[i][7]);
        }
        __syncthreads();

        // ---------------- async A: issue next chunk's X loads (early) -------
        if (cc + 1 < NCHUNK) {
            const int t0n    = (cc + 1) * TW;
            const int validn = (T_ - t0n < TW) ? (T_ - t0n) : TW;
            const int tsrc   = t0n + ((tl < validn) ? tl : (validn - 1));
            const float* Xrow = Xb + (size_t)tsrc * 256;
#pragma unroll
            for (int r = 0; r < 16; ++r)
                ra[r] = *(const float4*)(Xrow + r * 16 + wq);
        }

        // ---------------- phase S: scan (fmaf-canonicalized + ballot) -------
        {
            float Inx = Al[tid];         // q=0 prefetch
            for (int q = 0; q < valid; ++q) {
                const float Icur = Inx;
                if (q + 1 < valid) Inx = Al[(q + 1) * 256 + tid];
                const int t = t0 + q;
                const size_t pbase = (size_t)t * STP_ + boff;

                // canonical explicit-fma form of
                //   vm = v + (((v2_*v*v + v1_*v) + v0_ - u) + Icur)
                // replicating LLVM LHS-first contraction:
                const float m1 = v2_ * v;
                const float t2 = v1_ * v;
                const float P  = __builtin_fmaf(m1, v, t2);
                const float Q  = (P + v0_) - u;
                const float vm = v + (Q + Icur);
                //   um = u + coef*(b_*v - u)
                const float tb = __builtin_fmaf(b_, v, -u);
                const float um = __builtin_fmaf(coef, tb, u);

                const bool  sp = (vm - th_) > 0.f;
                const float s  = sp ? 1.f : 0.f;
                v = sp ? c_ : vm;        // == vm*(1-s)+s*c exactly, s in {0,1}
                u = sp ? (um + d_) : um; // == um + s*d

                states[pbase]           = v;
                states[pbase + BN_]     = u;
                states[pbase + 2 * BN_] = s;
                out_s[(size_t)t * BN_ + boff] = s;

                const unsigned long long mset = __ballot(sp);
                if (lane == 0) dotm[t][w] = mset;
            }
        }
        __syncthreads();                 // Al reads done before next A-stage
    }

    // ---------------- masks -> per-wave dots (parallel) ----------------
    for (int p = tid; p < T_ * 4; p += 256) {
        const int t  = p >> 2;
        const int ww = p & 3;
        unsigned long long m = dotm[t][ww];
        const float* wl = &w2l[ww << 6];
        float sum = 0.f;
        while (m) {
            const int i = __builtin_ctzll(m);
            sum += wl[i];
            m &= (m - 1);
        }
        dotf[t][ww] = sum;
    }
    __syncthreads();

    // ---------------- li recurrence (thread 0) ----------------
    if (tid == 0) {
        const float lk_  = pleak[0];
        const float olk_ = 1.0f - lk_;
        float li = st_li[bb];
        for (int t = 0; t < T_; ++t) {
            const float dot = (dotf[t][0] + dotf[t][1]) + (dotf[t][2] + dotf[t][3]);
            li = lk_ * li + olk_ * dot;
            out_dec[(size_t)t * 256 + bb] = li;
        }
    }
}

// ---------------------------------------------------------------------------
extern "C" void kernel_launch(void* const* d_in, const int* in_sizes, int n_in,
                              void* d_out, int out_size, void* d_ws, size_t ws_size,
                              hipStream_t stream) {
    const float* input  = (const float*)d_in[0];   // [B,T,N]
    const float* st_snn = (const float*)d_in[1];   // [3,B,N]
    const float* st_li  = (const float*)d_in[2];   // [B,1]
    const float* W1     = (const float*)d_in[3];   // [N,N]
    const float* W2     = (const float*)d_in[4];   // [1,N]
    const float* pa     = (const float*)d_in[5];
    const float* pb     = (const float*)d_in[6];
    const float* pc     = (const float*)d_in[7];
    const float* pd     = (const float*)d_in[8];
    const float* pv0    = (const float*)d_in[9];
    const float* pv1    = (const float*)d_in[10];
    const float* pv2    = (const float*)d_in[11];
    const float* ptau   = (const float*)d_in[12];
    const float* pth    = (const float*)d_in[13];
    const float* pleak  = (const float*)d_in[14];

    float* out        = (float*)d_out;
    float* out_s      = out;                                        // [500,256,256]
    float* out_states = out + (size_t)T_ * BN_;                     // [500,3,256,256]
    float* out_dec    = out + (size_t)T_ * BN_ + (size_t)T_ * STP_; // [500,256]

    fused_snn_kernel<<<dim3(B_), dim3(256), 0, stream>>>(
        input, W1, out_s, out_states, out_dec, st_snn, st_li, W2,
        pa, pb, pc, pd, pv0, pv1, pv2, ptau, pth, pleak);
}